// Round 6
// baseline (147.780 us; speedup 1.0000x reference)
//
#include <hip/hip_runtime.h>
#include <stdint.h>
#include <limits.h>

#define BATCH 4
#define N1D   2048
#define N2D   8192
#define NSAMP 32
#define NKP   15
#define CIN   64
#define COUT  128

#define RAD2    0.01f     // RADIUS^2
#define INV_EXT 25.0f     // 1 / EXTENT (EXTENT = 0.04)
#define BN_EPS  1e-5f
#define CMARG   0.1000001f  // cell-range margin (covers f32 rounding)

#define QPW   1                 // queries per wave
#define NWAVE 4                 // waves per block (block = 256)
#define QPB   (QPW*NWAVE)       // 4 queries per block
#define NCELL 1000              // 10x10x10 grid, cell = RADIUS
#define MAXC  96                // candidate cap (Poisson mean ~34, +10 sigma)

// ---- ws layout (in floats) ----
#define WS_PTS4   0                 // float4[B*N2]  raw coords      131072
#define WS_BPTS   131072            // float4[B*N2]  binned (x,y,z,j) 131072
#define WS_FEATT  262144            // float [B*N2*CIN]             2097152
#define WS_WT     2359296           // float [CIN*COUT] Wt[c][o]       8192
#define WS_OUT2   2367488           // float [B*COUT*N1]            1048576
#define WS_CS     3416064           // int [B*(NCELL+1)] cell starts   4004
#define WS_CNT    3420160           // int [B*1024] cell counts        4096
#define WS_CUR    3424256           // int [B*1024] scatter cursors    4096

__device__ __forceinline__ int cell_of(float x, float y, float z) {
  int cx = (int)(x*10.f); cx = cx < 0 ? 0 : (cx > 9 ? 9 : cx);
  int cy = (int)(y*10.f); cy = cy < 0 ? 0 : (cy > 9 ? 9 : cy);
  int cz = (int)(z*10.f); cz = cz < 0 ? 0 : (cz > 9 ? 9 : cz);
  return (cx*10 + cy)*10 + cz;
}

// ---------------------------------------------------------------------------
// prep: blocks 0-511 feature transpose (LDS-tiled) + point packing;
//       block 512 W transpose; blocks 513-640 cell counting (global atomics,
//       concurrent with the transpose blocks).  grid = 641 x 256.
// ---------------------------------------------------------------------------
__global__ __launch_bounds__(256) void pg_prep(
    const float* __restrict__ sxyz, const float* __restrict__ smask,
    const float* __restrict__ sfeat, const float* __restrict__ Wout,
    float4* __restrict__ pts4, float* __restrict__ featT, float* __restrict__ Wt,
    int* __restrict__ cellCnt)
{
  __shared__ float tile[64*65];
  const int t  = threadIdx.x;
  const int bt = blockIdx.x;

  if (bt == 512) {        // Wt[c][o] = W[o][c]
#pragma unroll
    for (int i = 0; i < 32; ++i) {
      const int flat = i*256 + t;            // flat = c*128 + o
      Wt[flat] = Wout[(flat & 127)*CIN + (flat >> 7)];
    }
    return;
  }

  if (bt >= 513) {        // ---- cell counting: 1 point per thread ----
    const int idx = bt - 513;                // [0,128)
    const int bb  = idx >> 5;
    const int i   = ((idx & 31) << 8) + t;   // [0,8192)
    if (smask[bb*N2D + i] > 0.f) {
      const float* p = sxyz + ((size_t)bb*N2D + i)*3;
      atomicAdd(&cellCnt[bb*1024 + cell_of(p[0], p[1], p[2])], 1);
    }
    return;
  }

  // ---- feature transpose tile + raw point packing ----
  const int b  = bt >> 7;
  const int j0 = (bt & 127) * 64;
  if (t < 64) {
    const int g = bt*64 + t;          // 512*64 = B*N2
    pts4[g] = make_float4(sxyz[g*3+0], sxyz[g*3+1], sxyz[g*3+2], 0.f);
  }
  const float* src = sfeat + (size_t)(b*CIN)*N2D + j0;
#pragma unroll
  for (int i = 0; i < 4; ++i) {
    const int c  = i*16 + (t >> 4);
    const int j4 = (t & 15) * 4;
    const float4 v = *(const float4*)(src + (size_t)c*N2D + j4);
    tile[c*65 + j4+0] = v.x;
    tile[c*65 + j4+1] = v.y;
    tile[c*65 + j4+2] = v.z;
    tile[c*65 + j4+3] = v.w;
  }
  __syncthreads();
  float* dstb = featT + (size_t)(b*N2D + j0) * CIN;
#pragma unroll
  for (int r = 0; r < 4; ++r) {
    const int j  = r*16 + (t >> 4);
    const int c4 = (t & 15) * 4;
    float4 v;
    v.x = tile[(c4+0)*65 + j];
    v.y = tile[(c4+1)*65 + j];
    v.z = tile[(c4+2)*65 + j];
    v.w = tile[(c4+3)*65 + j];
    *(float4*)(dstb + j*CIN + c4) = v;
  }
}

// ---------------------------------------------------------------------------
// scan: per-batch exclusive scan of 1000 cell counts -> cellStart + cursors.
// grid = 4 x 256.
// ---------------------------------------------------------------------------
__global__ __launch_bounds__(256) void pg_scan(
    const int* __restrict__ cellCnt, int* __restrict__ cellStart,
    int* __restrict__ cellCur)
{
  __shared__ int off_s[NCELL+1];
  __shared__ int wsum[4];
  const int t    = threadIdx.x;
  const int lane = t & 63;
  const int wv   = t >> 6;
  const int bb   = blockIdx.x;
  const int* cnt = cellCnt + bb*1024;

  int c0 = 0, c1 = 0, c2 = 0, c3 = 0, v = 0;
  if (t < 250) {
    c0 = cnt[t*4+0]; c1 = cnt[t*4+1]; c2 = cnt[t*4+2]; c3 = cnt[t*4+3];
    v = c0 + c1 + c2 + c3;
  }
  int x = v;
#pragma unroll
  for (int off = 1; off < 64; off <<= 1) {
    int y = __shfl_up(x, off);
    if (lane >= off) x += y;
  }
  if (lane == 63) wsum[wv] = x;
  __syncthreads();
  int base = 0;
#pragma unroll
  for (int w = 0; w < 4; ++w) if (w < wv) base += wsum[w];
  const int excl = base + x - v;
  if (t < 250) {
    int o = excl;
    off_s[t*4+0] = o; o += c0;
    off_s[t*4+1] = o; o += c1;
    off_s[t*4+2] = o; o += c2;
    off_s[t*4+3] = o;
  }
  if (t == 0) off_s[NCELL] = wsum[0]+wsum[1]+wsum[2]+wsum[3];
  __syncthreads();
  for (int i = t; i < NCELL; i += 256) {
    const int o = off_s[i];
    cellStart[bb*(NCELL+1) + i] = o;
    cellCur[bb*1024 + i] = o;
  }
  if (t == 0) cellStart[bb*(NCELL+1) + NCELL] = off_s[NCELL];
}

// ---------------------------------------------------------------------------
// scatter: place points into bins via global cursors.  grid = 128 x 256.
// ---------------------------------------------------------------------------
__global__ __launch_bounds__(256) void pg_scatter(
    const float* __restrict__ sxyz, const float* __restrict__ smask,
    int* __restrict__ cellCur, float4* __restrict__ bpts)
{
  const int idx = blockIdx.x;
  const int bb  = idx >> 5;
  const int i   = ((idx & 31) << 8) + threadIdx.x;
  if (smask[bb*N2D + i] > 0.f) {
    const float* p = sxyz + ((size_t)bb*N2D + i)*3;
    const float px = p[0], py = p[1], pz = p[2];
    const int pos = atomicAdd(&cellCur[bb*1024 + cell_of(px,py,pz)], 1);
    bpts[(size_t)bb*N2D + pos] = make_float4(px, py, pz, __int_as_float(i));
  }
}

// ---------------------------------------------------------------------------
// main: binned ordered ball query + kernel-point weights + weighted feature
//       sum + fused 1x1 conv.  grid = 2048 x 256 (4 queries/block, 1/wave).
// LDS ~18 KB -> 8 blocks/CU (grid/CU = 8): occupancy cap 100%.
// ---------------------------------------------------------------------------
__global__ __launch_bounds__(256) void pg_main(
    const float* __restrict__ qxyz, const float* __restrict__ qmask,
    const float4* __restrict__ pts4, const float4* __restrict__ bpts,
    const int* __restrict__ cellStart, const float* __restrict__ featT,
    const float* __restrict__ Kp, const float* __restrict__ KW,
    const float* __restrict__ Wt, float* __restrict__ out2)
{
  __shared__ int      s_cs[NCELL+1];         // 4 KB cell starts (this batch)
  __shared__ int      s_cand[QPB][MAXC];     // 1.5 KB candidate j lists
  __shared__ int      s_idx[QPB*NSAMP];      // 0.5 KB
  __shared__ int      s_cnt[QPB];
  __shared__ float    s_w[QPB*NSAMP*17];     // 8.7 KB (pad 17)
  __shared__ unsigned s_wm[QPB*NSAMP];       // 0.5 KB active-k bitmasks
  __shared__ float    s_xq[QPB*65];          // 1 KB fused-conv x rows

  const int t    = threadIdx.x;
  const int lane = t & 63;
  const int wv   = t >> 6;
  const int gbase = blockIdx.x * QPB;        // 2048 % 4 == 0 -> single batch
  const int b     = gbase >> 11;
  const uint64_t lt = (1ull << lane) - 1ull;

  for (int i = t; i < NCELL+1; i += 256) s_cs[i] = cellStart[b*(NCELL+1) + i];
  __syncthreads();

  // ---- phase 1: one query per wave: candidate collection + rank select ----
  const float4* bptsb = bpts + (size_t)b*N2D;
  {
    const int ql = wv;
    const int g  = gbase + ql;
    const float qx = qxyz[g*3+0], qy = qxyz[g*3+1], qz = qxyz[g*3+2];
    int cx0 = (int)((qx-CMARG)*10.f); if (cx0 < 0) cx0 = 0;
    int cx1 = (int)((qx+CMARG)*10.f); if (cx1 > 9) cx1 = 9;
    int cy0 = (int)((qy-CMARG)*10.f); if (cy0 < 0) cy0 = 0;
    int cy1 = (int)((qy+CMARG)*10.f); if (cy1 > 9) cy1 = 9;
    int cz0 = (int)((qz-CMARG)*10.f); if (cz0 < 0) cz0 = 0;
    int cz1 = (int)((qz+CMARG)*10.f); if (cz1 > 9) cz1 = 9;

    int ccnt = 0;
    for (int cx = cx0; cx <= cx1; ++cx) {
      for (int cy = cy0; cy <= cy1; ++cy) {
        const int rowb = (cx*10 + cy)*10;
        const int rs = s_cs[rowb + cz0];
        const int re = s_cs[rowb + cz1 + 1];
        for (int base = rs; base < re; base += 64) {
          const int ii = base + lane;
          bool ok = false; int jj = 0;
          if (ii < re) {
            const float4 p = bptsb[ii];
            const float dx = p.x - qx, dy = p.y - qy, dz = p.z - qz;
            ok = (dx*dx + dy*dy + dz*dz) < RAD2;
            jj = __float_as_int(p.w);
          }
          const uint64_t m = __ballot(ok);
          if (ok) {
            const int pos = ccnt + __popcll(m & lt);
            if (pos < MAXC) s_cand[ql][pos] = jj;
          }
          ccnt += (int)__popcll(m);
        }
      }
    }
    const int C = ccnt < MAXC ? ccnt : MAXC;
    // rank-select 32 smallest j (== first 32 in scan order)
    int jA = (lane      < C) ? s_cand[ql][lane]      : INT_MAX;
    int jB = (lane + 64 < C) ? s_cand[ql][lane + 64] : INT_MAX;
    int rA = 0, rB = 0;
    for (int e = 0; e < C; ++e) {
      const int je = s_cand[ql][e];      // broadcast read
      rA += (je < jA);
      rB += (je < jB);
    }
    if (lane      < C && rA < NSAMP) s_idx[ql*NSAMP + rA] = jA;
    if (lane + 64 < C && rB < NSAMP) s_idx[ql*NSAMP + rB] = jB;
    if (lane == 0) s_cnt[ql] = C < NSAMP ? C : NSAMP;
  }
  __syncthreads();

  // ---- phase 2a: pad-normalize idx, rel vector, per-(q,s,k) weights ----
  if (t < QPB*NSAMP) {                        // 128 slots
    const int qslot = t >> 5;
    const int s = t & 31;
    const int c = s_cnt[qslot];
    int j;
    if (s < c) {
      j = s_idx[t];
    } else {
      j = (c > 0) ? s_idx[qslot*NSAMP] : 0;   // pad with first neighbor
      s_idx[t] = j;
    }
    const int g = gbase + qslot;
    const float4 pj = pts4[b*N2D + j];
    const float rx = pj.x - qxyz[g*3+0];
    const float ry = pj.y - qxyz[g*3+1];
    const float rz = pj.z - qxyz[g*3+2];

    unsigned msk = 0u;
#pragma unroll
    for (int k = 0; k < NKP; ++k) {           // k uniform -> Kp scalar loads
      const float dx = rx - Kp[k*3+0];
      const float dy = ry - Kp[k*3+1];
      const float dz = rz - Kp[k*3+2];
      const float dd = dx*dx + dy*dy + dz*dz;
      const float w = 1.0f - sqrtf(dd) * INV_EXT;
      if (w > 0.0f) {
        s_w[t*17 + k] = w;
        msk |= (1u << k);
      }
    }
    s_wm[t] = msk;
  }
  __syncthreads();

  // ---- phase 2b: weighted feature aggregation (lane = channel) ----
  float kw[NKP];
#pragma unroll
  for (int k = 0; k < NKP; ++k) kw[k] = KW[k*CIN + lane];

  {
    const int ql = wv;
    const int g = gbase + ql;
    const float fpad = 1.0f - qmask[g];
    const int c = __builtin_amdgcn_readfirstlane(s_cnt[ql]);

    float ft[NSAMP];
#pragma unroll
    for (int s = 0; s < NSAMP; ++s) {
      const int j = __builtin_amdgcn_readfirstlane(s_idx[ql*NSAMP + s]);
      ft[s] = featT[(size_t)(b*N2D + j)*CIN + lane];
    }

    float acc = 0.0f;
#pragma unroll
    for (int s = 0; s < NSAMP; ++s) {
      const float fm = ((s < c) ? 1.0f : 0.0f) + fpad;
      if (fm != 0.0f) {
        const unsigned mk =
            (unsigned)__builtin_amdgcn_readfirstlane((int)s_wm[ql*NSAMP + s]);
        if (mk != 0u) {
          const float* wp = &s_w[(ql*NSAMP + s)*17];
          float wsum = 0.0f;
#pragma unroll
          for (int k = 0; k < NKP; ++k)
            if (mk & (1u << k)) wsum += wp[k] * kw[k];
          acc = fmaf(fm*wsum, ft[s], acc);
        }
      }
    }
    s_xq[ql*65 + lane] = acc;
  }
  __syncthreads();

  // ---- epilogue: fused 1x1 conv, 256 threads x 2 outputs ----
  // thread t: query slot n4 = t&3, o-group og = t>>2 (outputs og*2, og*2+1)
  {
    const int n4 = t & 3;
    const int og = t >> 2;
    const int g  = gbase + n4;
    const int nn = g & 2047;
    float a0 = 0.f, a1 = 0.f;
#pragma unroll
    for (int c = 0; c < CIN; ++c) {
      const float xc = s_xq[n4*65 + c];                        // 4-addr broadcast
      const float2 w2 = *(const float2*)(Wt + c*COUT + og*2);  // L1-hot
      a0 = fmaf(w2.x, xc, a0);
      a1 = fmaf(w2.y, xc, a1);
    }
    float* ob = out2 + (size_t)(b*COUT + og*2)*N1D + nn;
    ob[0]   = a0;
    ob[N1D] = a1;
  }
}

// ---------------------------------------------------------------------------
// finish: per-(b,o) block; redundantly computes channel-o batch stats from
// L2-hot out2, then normalizes its own row from registers.  grid = 512 x 256.
// ---------------------------------------------------------------------------
__global__ __launch_bounds__(256) void pg_finish(
    const float* __restrict__ out2, const float* __restrict__ gamma,
    const float* __restrict__ beta, float* __restrict__ dout)
{
  __shared__ float red[8];
  __shared__ float mv[2];
  const int t  = threadIdx.x;
  const int o  = blockIdx.x & 127;
  const int bb = blockIdx.x >> 7;
  float4 f[4][2];
  float s1 = 0.f, s2 = 0.f;
#pragma unroll
  for (int r = 0; r < BATCH; ++r) {
    const float4* p = (const float4*)(out2 + (size_t)(r*COUT + o)*N1D);
#pragma unroll
    for (int i = 0; i < 2; ++i) {
      const float4 x = p[i*256 + t];
      f[r][i] = x;
      s1 += x.x + x.y + x.z + x.w;
      s2 += x.x*x.x + x.y*x.y + x.z*x.z + x.w*x.w;
    }
  }
#pragma unroll
  for (int off = 32; off; off >>= 1) {
    s1 += __shfl_xor(s1, off);
    s2 += __shfl_xor(s2, off);
  }
  const int wv = t >> 6;
  if ((t & 63) == 0) { red[wv] = s1; red[4+wv] = s2; }
  __syncthreads();
  if (t == 0) {
    const float inv = 1.0f / (float)(BATCH*N1D);
    const float mean = (red[0]+red[1]+red[2]+red[3]) * inv;
    const float var  = (red[4]+red[5]+red[6]+red[7]) * inv - mean*mean;
    mv[0] = mean;
    mv[1] = rsqrtf(var + BN_EPS);
  }
  __syncthreads();
  const float mean = mv[0];
  const float ga = gamma[o] * mv[1];
  const float be = beta[o];
  float4* dp = (float4*)(dout + (size_t)(bb*COUT + o)*N1D);
#pragma unroll
  for (int i = 0; i < 2; ++i) {
    const float4 x = f[bb][i];
    float4 y;
    y.x = fmaxf((x.x - mean)*ga + be, 0.0f);
    y.y = fmaxf((x.y - mean)*ga + be, 0.0f);
    y.z = fmaxf((x.z - mean)*ga + be, 0.0f);
    y.w = fmaxf((x.w - mean)*ga + be, 0.0f);
    dp[i*256 + t] = y;
  }
}

extern "C" void kernel_launch(void* const* d_in, const int* in_sizes, int n_in,
                              void* d_out, int out_size, void* d_ws, size_t ws_size,
                              hipStream_t stream)
{
  const float* qxyz  = (const float*)d_in[0];
  const float* sxyz  = (const float*)d_in[1];
  const float* qmask = (const float*)d_in[2];
  const float* smask = (const float*)d_in[3];
  const float* sfeat = (const float*)d_in[4];
  const float* Kp    = (const float*)d_in[5];
  const float* KW    = (const float*)d_in[6];
  const float* Wout  = (const float*)d_in[7];
  const float* gamma = (const float*)d_in[8];
  const float* beta  = (const float*)d_in[9];
  float* ws = (float*)d_ws;
  float4* pts4 = (float4*)(ws + WS_PTS4);
  float4* bpts = (float4*)(ws + WS_BPTS);
  float* featT = ws + WS_FEATT;
  float* Wt    = ws + WS_WT;
  float* out2  = ws + WS_OUT2;
  int*   cellS = (int*)(ws + WS_CS);
  int*   cellC = (int*)(ws + WS_CNT);
  int*   cellU = (int*)(ws + WS_CUR);
  float* dst   = (float*)d_out;

  hipMemsetAsync(cellC, 0, BATCH*1024*sizeof(int), stream);
  pg_prep   <<<641,  256, 0, stream>>>(sxyz, smask, sfeat, Wout, pts4, featT,
                                       Wt, cellC);
  pg_scan   <<<4,    256, 0, stream>>>(cellC, cellS, cellU);
  pg_scatter<<<128,  256, 0, stream>>>(sxyz, smask, cellU, bpts);
  pg_main   <<<2048, 256, 0, stream>>>(qxyz, qmask, pts4, bpts, cellS, featT,
                                       Kp, KW, Wt, out2);
  pg_finish <<<512,  256, 0, stream>>>(out2, gamma, beta, dst);
}

// Round 7
// 144.899 us; speedup vs baseline: 1.0199x; 1.0199x over previous
//
#include <hip/hip_runtime.h>
#include <stdint.h>
#include <limits.h>

#define BATCH 4
#define N1D   2048
#define N2D   8192
#define NSAMP 32
#define NKP   15
#define CIN   64
#define COUT  128

#define RAD2    0.01f     // RADIUS^2
#define INV_EXT 25.0f     // 1 / EXTENT (EXTENT = 0.04)
#define BN_EPS  1e-5f
#define CMARG   0.1000001f  // cell-range margin (covers f32 rounding)

#define QPW   1                 // queries per wave
#define NWAVE 4                 // waves per block (block = 256)
#define QPB   (QPW*NWAVE)       // 4 queries per block
#define NCELL 1000              // 10x10x10 grid, cell = RADIUS
#define MAXC  96                // candidate cap (Poisson mean ~34, +10 sigma)

// ---- ws layout (in floats) ----
#define WS_PTS4   0                 // float4[B*N2]  raw coords      131072
#define WS_BPTS   131072            // float4[B*N2]  binned (x,y,z,j) 131072
#define WS_FEATT  262144            // float [B*N2*CIN]             2097152
#define WS_WT     2359296           // float [CIN*COUT] Wt[c][o]       8192
#define WS_OUT2   2367488           // float [B*COUT*N1]            1048576
#define WS_CS     3416064           // int [B*(NCELL+1)] cell starts   4004
#define WS_CNT    3420160           // int [B*1024] cell counts        4096
#define WS_CUR    3424256           // int [B*1024] scatter cursors    4096

__device__ __forceinline__ int cell_of(float x, float y, float z) {
  int cx = (int)(x*10.f); cx = cx < 0 ? 0 : (cx > 9 ? 9 : cx);
  int cy = (int)(y*10.f); cy = cy < 0 ? 0 : (cy > 9 ? 9 : cy);
  int cz = (int)(z*10.f); cz = cz < 0 ? 0 : (cz > 9 ? 9 : cz);
  return (cx*10 + cy)*10 + cz;
}

// ---------------------------------------------------------------------------
// prep: blocks 0-511 feature transpose (LDS-tiled) + point packing;
//       block 512 W transpose; blocks 513-640 cell counting (global atomics,
//       concurrent with the transpose blocks).  grid = 641 x 256.
// ---------------------------------------------------------------------------
__global__ __launch_bounds__(256) void pg_prep(
    const float* __restrict__ sxyz, const float* __restrict__ smask,
    const float* __restrict__ sfeat, const float* __restrict__ Wout,
    float4* __restrict__ pts4, float* __restrict__ featT, float* __restrict__ Wt,
    int* __restrict__ cellCnt)
{
  __shared__ float tile[64*65];
  const int t  = threadIdx.x;
  const int bt = blockIdx.x;

  if (bt == 512) {        // Wt[c][o] = W[o][c]
#pragma unroll
    for (int i = 0; i < 32; ++i) {
      const int flat = i*256 + t;            // flat = c*128 + o
      Wt[flat] = Wout[(flat & 127)*CIN + (flat >> 7)];
    }
    return;
  }

  if (bt >= 513) {        // ---- cell counting: 1 point per thread ----
    const int idx = bt - 513;                // [0,128)
    const int bb  = idx >> 5;
    const int i   = ((idx & 31) << 8) + t;   // [0,8192)
    if (smask[bb*N2D + i] > 0.f) {
      const float* p = sxyz + ((size_t)bb*N2D + i)*3;
      atomicAdd(&cellCnt[bb*1024 + cell_of(p[0], p[1], p[2])], 1);
    }
    return;
  }

  // ---- feature transpose tile + raw point packing ----
  const int b  = bt >> 7;
  const int j0 = (bt & 127) * 64;
  if (t < 64) {
    const int g = bt*64 + t;          // 512*64 = B*N2
    pts4[g] = make_float4(sxyz[g*3+0], sxyz[g*3+1], sxyz[g*3+2], 0.f);
  }
  const float* src = sfeat + (size_t)(b*CIN)*N2D + j0;
#pragma unroll
  for (int i = 0; i < 4; ++i) {
    const int c  = i*16 + (t >> 4);
    const int j4 = (t & 15) * 4;
    const float4 v = *(const float4*)(src + (size_t)c*N2D + j4);
    tile[c*65 + j4+0] = v.x;
    tile[c*65 + j4+1] = v.y;
    tile[c*65 + j4+2] = v.z;
    tile[c*65 + j4+3] = v.w;
  }
  __syncthreads();
  float* dstb = featT + (size_t)(b*N2D + j0) * CIN;
#pragma unroll
  for (int r = 0; r < 4; ++r) {
    const int j  = r*16 + (t >> 4);
    const int c4 = (t & 15) * 4;
    float4 v;
    v.x = tile[(c4+0)*65 + j];
    v.y = tile[(c4+1)*65 + j];
    v.z = tile[(c4+2)*65 + j];
    v.w = tile[(c4+3)*65 + j];
    *(float4*)(dstb + j*CIN + c4) = v;
  }
}

// ---------------------------------------------------------------------------
// scan: per-batch exclusive scan of 1000 cell counts -> cellStart + cursors.
// grid = 4 x 256.
// ---------------------------------------------------------------------------
__global__ __launch_bounds__(256) void pg_scan(
    const int* __restrict__ cellCnt, int* __restrict__ cellStart,
    int* __restrict__ cellCur)
{
  __shared__ int off_s[NCELL+1];
  __shared__ int wsum[4];
  const int t    = threadIdx.x;
  const int lane = t & 63;
  const int wv   = t >> 6;
  const int bb   = blockIdx.x;
  const int* cnt = cellCnt + bb*1024;

  int c0 = 0, c1 = 0, c2 = 0, c3 = 0, v = 0;
  if (t < 250) {
    c0 = cnt[t*4+0]; c1 = cnt[t*4+1]; c2 = cnt[t*4+2]; c3 = cnt[t*4+3];
    v = c0 + c1 + c2 + c3;
  }
  int x = v;
#pragma unroll
  for (int off = 1; off < 64; off <<= 1) {
    int y = __shfl_up(x, off);
    if (lane >= off) x += y;
  }
  if (lane == 63) wsum[wv] = x;
  __syncthreads();
  int base = 0;
#pragma unroll
  for (int w = 0; w < 4; ++w) if (w < wv) base += wsum[w];
  const int excl = base + x - v;
  if (t < 250) {
    int o = excl;
    off_s[t*4+0] = o; o += c0;
    off_s[t*4+1] = o; o += c1;
    off_s[t*4+2] = o; o += c2;
    off_s[t*4+3] = o;
  }
  if (t == 0) off_s[NCELL] = wsum[0]+wsum[1]+wsum[2]+wsum[3];
  __syncthreads();
  for (int i = t; i < NCELL; i += 256) {
    const int o = off_s[i];
    cellStart[bb*(NCELL+1) + i] = o;
    cellCur[bb*1024 + i] = o;
  }
  if (t == 0) cellStart[bb*(NCELL+1) + NCELL] = off_s[NCELL];
}

// ---------------------------------------------------------------------------
// scatter: place points into bins via global cursors.  grid = 128 x 256.
// ---------------------------------------------------------------------------
__global__ __launch_bounds__(256) void pg_scatter(
    const float* __restrict__ sxyz, const float* __restrict__ smask,
    int* __restrict__ cellCur, float4* __restrict__ bpts)
{
  const int idx = blockIdx.x;
  const int bb  = idx >> 5;
  const int i   = ((idx & 31) << 8) + threadIdx.x;
  if (smask[bb*N2D + i] > 0.f) {
    const float* p = sxyz + ((size_t)bb*N2D + i)*3;
    const float px = p[0], py = p[1], pz = p[2];
    const int pos = atomicAdd(&cellCur[bb*1024 + cell_of(px,py,pz)], 1);
    bpts[(size_t)bb*N2D + pos] = make_float4(px, py, pz, __int_as_float(i));
  }
}

// ---------------------------------------------------------------------------
// main: binned ordered ball query (flat-index candidate walk) + kernel-point
// weights + weighted feature sum + fused 1x1 conv.
// grid = 2048 x 256 (4 queries/block, 1/wave).  LDS ~13 KB.
// ---------------------------------------------------------------------------
__global__ __launch_bounds__(256) void pg_main(
    const float* __restrict__ qxyz, const float* __restrict__ qmask,
    const float4* __restrict__ pts4, const float4* __restrict__ bpts,
    const int* __restrict__ cellStart, const float* __restrict__ featT,
    const float* __restrict__ Kp, const float* __restrict__ KW,
    const float* __restrict__ Wt, float* __restrict__ out2)
{
  __shared__ int      s_segb[QPB][12];       // per-wave: rs - excl, per pair
  __shared__ int      s_segc[QPB][12];       // per-wave: cumulative boundaries
  __shared__ int      s_cand[QPB][MAXC];     // 1.5 KB candidate j lists (16B-aligned rows)
  __shared__ int      s_idx[QPB*NSAMP];      // 0.5 KB
  __shared__ int      s_cnt[QPB];
  __shared__ float    s_w[QPB*NSAMP*17];     // 8.7 KB (pad 17)
  __shared__ unsigned s_wm[QPB*NSAMP];       // 0.5 KB active-k bitmasks
  __shared__ float    s_xq[QPB*65];          // 1 KB fused-conv x rows

  const int t    = threadIdx.x;
  const int lane = t & 63;
  const int wv   = t >> 6;
  const int gbase = blockIdx.x * QPB;        // 2048 % 4 == 0 -> single batch
  const int b     = gbase >> 11;
  const uint64_t lt = (1ull << lane) - 1ull;

  // ---- phase 1: one query per wave, flat-index candidate walk ----
  const float4* bptsb = bpts + (size_t)b*N2D;
  {
    const int ql = wv;
    const int g  = gbase + ql;
    const float qx = qxyz[g*3+0], qy = qxyz[g*3+1], qz = qxyz[g*3+2];
    int cx0 = (int)((qx-CMARG)*10.f); if (cx0 < 0) cx0 = 0;
    int cx1 = (int)((qx+CMARG)*10.f); if (cx1 > 9) cx1 = 9;
    int cy0 = (int)((qy-CMARG)*10.f); if (cy0 < 0) cy0 = 0;
    int cy1 = (int)((qy+CMARG)*10.f); if (cy1 > 9) cy1 = 9;
    int cz0 = (int)((qz-CMARG)*10.f); if (cz0 < 0) cz0 = 0;
    int cz1 = (int)((qz+CMARG)*10.f); if (cz1 > 9) cz1 = 9;
    const int ny = cy1 - cy0 + 1;
    const int npair = (cx1 - cx0 + 1) * ny;  // <= 9

    // lanes 0..npair-1 fetch their pair's [rs,re) from L2-hot cellStart
    int len = 0, rs = 0;
    if (lane < npair) {
      const int cx = cx0 + lane / ny;
      const int cy = cy0 + lane % ny;
      const int rowb = (cx*10 + cy)*10;
      const int* csb = cellStart + b*(NCELL+1) + rowb;
      rs = csb[cz0];
      len = csb[cz1 + 1] - rs;
    }
    // shfl prefix over lanes (only first npair nonzero; lane15 holds total)
    int c = len;
#pragma unroll
    for (int off = 1; off < 16; off <<= 1) {
      int y = __shfl_up(c, off);
      if (lane >= off) c += y;
    }
    const int tot = __shfl(c, 15);
    const int excl = c - len;
    if (lane < npair) s_segb[ql][lane] = rs - excl;
    if (lane <= npair) s_segc[ql][lane] = excl;   // lane==npair writes tot

    int ccnt = 0;
    for (int base = 0; base < tot; base += 64) {
      const int idx = base + lane;
      bool ok = false; int jj = 0;
      if (idx < tot) {
        int p = 0;
        while (s_segc[ql][p+1] <= idx) ++p;       // <= 8 iters, LDS broadcast
        const float4 pt = bptsb[s_segb[ql][p] + idx];
        const float dx = pt.x - qx, dy = pt.y - qy, dz = pt.z - qz;
        ok = (dx*dx + dy*dy + dz*dz) < RAD2;
        jj = __float_as_int(pt.w);
      }
      const uint64_t m = __ballot(ok);
      if (ok) {
        const int pos = ccnt + __popcll(m & lt);
        if (pos < MAXC) s_cand[ql][pos] = jj;
      }
      ccnt += (int)__popcll(m);
    }
    const int C = ccnt < MAXC ? ccnt : MAXC;
    const int C4 = (C + 3) & ~3;
    if (C + lane < C4) s_cand[ql][C + lane] = INT_MAX;  // pad to x4

    // rank-select 32 smallest j via int4 LDS reads
    int jA = (lane      < C) ? s_cand[ql][lane]      : INT_MAX;
    int jB = (lane + 64 < C) ? s_cand[ql][lane + 64] : INT_MAX;
    int rA = 0, rB = 0;
    for (int e = 0; e < C4; e += 4) {
      const int4 v4 = *(const int4*)&s_cand[ql][e];
      rA += (v4.x < jA) + (v4.y < jA) + (v4.z < jA) + (v4.w < jA);
      rB += (v4.x < jB) + (v4.y < jB) + (v4.z < jB) + (v4.w < jB);
    }
    if (lane      < C && rA < NSAMP) s_idx[ql*NSAMP + rA] = jA;
    if (lane + 64 < C && rB < NSAMP) s_idx[ql*NSAMP + rB] = jB;
    if (lane == 0) s_cnt[ql] = C < NSAMP ? C : NSAMP;
  }
  __syncthreads();

  // ---- phase 2a: pad-normalize idx, rel vector, per-(q,s,k) weights ----
  if (t < QPB*NSAMP) {                        // 128 slots
    const int qslot = t >> 5;
    const int s = t & 31;
    const int c = s_cnt[qslot];
    int j;
    if (s < c) {
      j = s_idx[t];
    } else {
      j = (c > 0) ? s_idx[qslot*NSAMP] : 0;   // pad with first neighbor
      s_idx[t] = j;
    }
    const int g = gbase + qslot;
    const float4 pj = pts4[b*N2D + j];
    const float rx = pj.x - qxyz[g*3+0];
    const float ry = pj.y - qxyz[g*3+1];
    const float rz = pj.z - qxyz[g*3+2];

    unsigned msk = 0u;
#pragma unroll
    for (int k = 0; k < NKP; ++k) {           // k uniform -> Kp scalar loads
      const float dx = rx - Kp[k*3+0];
      const float dy = ry - Kp[k*3+1];
      const float dz = rz - Kp[k*3+2];
      const float dd = dx*dx + dy*dy + dz*dz;
      const float w = 1.0f - sqrtf(dd) * INV_EXT;
      if (w > 0.0f) {
        s_w[t*17 + k] = w;
        msk |= (1u << k);
      }
    }
    s_wm[t] = msk;
  }
  __syncthreads();

  // ---- phase 2b: weighted feature aggregation (lane = channel) ----
  float kw[NKP];
#pragma unroll
  for (int k = 0; k < NKP; ++k) kw[k] = KW[k*CIN + lane];

  {
    const int ql = wv;
    const int g = gbase + ql;
    const float fpad = 1.0f - qmask[g];
    const int c = __builtin_amdgcn_readfirstlane(s_cnt[ql]);

    float ft[NSAMP];
#pragma unroll
    for (int s = 0; s < NSAMP; ++s) {
      const int j = __builtin_amdgcn_readfirstlane(s_idx[ql*NSAMP + s]);
      ft[s] = featT[(size_t)(b*N2D + j)*CIN + lane];
    }

    float acc = 0.0f;
#pragma unroll
    for (int s = 0; s < NSAMP; ++s) {
      const float fm = ((s < c) ? 1.0f : 0.0f) + fpad;
      if (fm != 0.0f) {
        const unsigned mk =
            (unsigned)__builtin_amdgcn_readfirstlane((int)s_wm[ql*NSAMP + s]);
        if (mk != 0u) {
          const float* wp = &s_w[(ql*NSAMP + s)*17];
          float wsum = 0.0f;
#pragma unroll
          for (int k = 0; k < NKP; ++k)
            if (mk & (1u << k)) wsum += wp[k] * kw[k];
          acc = fmaf(fm*wsum, ft[s], acc);
        }
      }
    }
    s_xq[ql*65 + lane] = acc;
  }
  __syncthreads();

  // ---- epilogue: fused 1x1 conv, 256 threads x 2 outputs ----
  {
    const int n4 = t & 3;
    const int og = t >> 2;
    const int g  = gbase + n4;
    const int nn = g & 2047;
    float a0 = 0.f, a1 = 0.f;
#pragma unroll
    for (int c = 0; c < CIN; ++c) {
      const float xc = s_xq[n4*65 + c];                        // 4-addr broadcast
      const float2 w2 = *(const float2*)(Wt + c*COUT + og*2);  // L1-hot
      a0 = fmaf(w2.x, xc, a0);
      a1 = fmaf(w2.y, xc, a1);
    }
    float* ob = out2 + (size_t)(b*COUT + og*2)*N1D + nn;
    ob[0]   = a0;
    ob[N1D] = a1;
  }
}

// ---------------------------------------------------------------------------
// finish: per-(b,o) block; redundantly computes channel-o batch stats from
// L2-hot out2, then normalizes its own row from registers.  grid = 512 x 256.
// ---------------------------------------------------------------------------
__global__ __launch_bounds__(256) void pg_finish(
    const float* __restrict__ out2, const float* __restrict__ gamma,
    const float* __restrict__ beta, float* __restrict__ dout)
{
  __shared__ float red[8];
  __shared__ float mv[2];
  const int t  = threadIdx.x;
  const int o  = blockIdx.x & 127;
  const int bb = blockIdx.x >> 7;
  float4 f[4][2];
  float s1 = 0.f, s2 = 0.f;
#pragma unroll
  for (int r = 0; r < BATCH; ++r) {
    const float4* p = (const float4*)(out2 + (size_t)(r*COUT + o)*N1D);
#pragma unroll
    for (int i = 0; i < 2; ++i) {
      const float4 x = p[i*256 + t];
      f[r][i] = x;
      s1 += x.x + x.y + x.z + x.w;
      s2 += x.x*x.x + x.y*x.y + x.z*x.z + x.w*x.w;
    }
  }
#pragma unroll
  for (int off = 32; off; off >>= 1) {
    s1 += __shfl_xor(s1, off);
    s2 += __shfl_xor(s2, off);
  }
  const int wv = t >> 6;
  if ((t & 63) == 0) { red[wv] = s1; red[4+wv] = s2; }
  __syncthreads();
  if (t == 0) {
    const float inv = 1.0f / (float)(BATCH*N1D);
    const float mean = (red[0]+red[1]+red[2]+red[3]) * inv;
    const float var  = (red[4]+red[5]+red[6]+red[7]) * inv - mean*mean;
    mv[0] = mean;
    mv[1] = rsqrtf(var + BN_EPS);
  }
  __syncthreads();
  const float mean = mv[0];
  const float ga = gamma[o] * mv[1];
  const float be = beta[o];
  float4* dp = (float4*)(dout + (size_t)(bb*COUT + o)*N1D);
#pragma unroll
  for (int i = 0; i < 2; ++i) {
    const float4 x = f[bb][i];
    float4 y;
    y.x = fmaxf((x.x - mean)*ga + be, 0.0f);
    y.y = fmaxf((x.y - mean)*ga + be, 0.0f);
    y.z = fmaxf((x.z - mean)*ga + be, 0.0f);
    y.w = fmaxf((x.w - mean)*ga + be, 0.0f);
    dp[i*256 + t] = y;
  }
}

extern "C" void kernel_launch(void* const* d_in, const int* in_sizes, int n_in,
                              void* d_out, int out_size, void* d_ws, size_t ws_size,
                              hipStream_t stream)
{
  const float* qxyz  = (const float*)d_in[0];
  const float* sxyz  = (const float*)d_in[1];
  const float* qmask = (const float*)d_in[2];
  const float* smask = (const float*)d_in[3];
  const float* sfeat = (const float*)d_in[4];
  const float* Kp    = (const float*)d_in[5];
  const float* KW    = (const float*)d_in[6];
  const float* Wout  = (const float*)d_in[7];
  const float* gamma = (const float*)d_in[8];
  const float* beta  = (const float*)d_in[9];
  float* ws = (float*)d_ws;
  float4* pts4 = (float4*)(ws + WS_PTS4);
  float4* bpts = (float4*)(ws + WS_BPTS);
  float* featT = ws + WS_FEATT;
  float* Wt    = ws + WS_WT;
  float* out2  = ws + WS_OUT2;
  int*   cellS = (int*)(ws + WS_CS);
  int*   cellC = (int*)(ws + WS_CNT);
  int*   cellU = (int*)(ws + WS_CUR);
  float* dst   = (float*)d_out;

  hipMemsetAsync(cellC, 0, BATCH*1024*sizeof(int), stream);
  pg_prep   <<<641,  256, 0, stream>>>(sxyz, smask, sfeat, Wout, pts4, featT,
                                       Wt, cellC);
  pg_scan   <<<4,    256, 0, stream>>>(cellC, cellS, cellU);
  pg_scatter<<<128,  256, 0, stream>>>(sxyz, smask, cellU, bpts);
  pg_main   <<<2048, 256, 0, stream>>>(qxyz, qmask, pts4, bpts, cellS, featT,
                                       Kp, KW, Wt, out2);
  pg_finish <<<512,  256, 0, stream>>>(out2, gamma, beta, dst);
}

// Round 8
// 132.296 us; speedup vs baseline: 1.1170x; 1.0953x over previous
//
#include <hip/hip_runtime.h>
#include <stdint.h>
#include <limits.h>

#define BATCH 4
#define N1D   2048
#define N2D   8192
#define NSAMP 32
#define NKP   15
#define CIN   64
#define COUT  128

#define RAD2    0.01f     // RADIUS^2
#define INV_EXT 25.0f     // 1 / EXTENT (EXTENT = 0.04)
#define BN_EPS  1e-5f
#define CMARG   0.1000001f  // cell-range margin (covers f32 rounding)

#define NWAVE 4                 // waves per block (block = 256)
#define QPB   NWAVE             // 4 queries per block, 1 per wave
#define NCELL 1000              // 10x10x10 grid, cell = RADIUS
#define MAXC  96                // candidate cap (ball count mean ~34)

// ---- ws layout (in floats) ----
#define WS_PTS4   0                 // float4[B*N2]  raw coords      131072
#define WS_BPTS   131072            // float4[B*N2]  binned (x,y,z,j) 131072
#define WS_FEATT  262144            // float [B*N2*CIN]             2097152
#define WS_OUT2   2367488           // float [B*COUT*N1]            1048576
#define WS_CS     3416064           // int [B*(NCELL+1)] cell starts   4004
#define WS_CNT    3420160           // int [B*1024] cell counts        4096
#define WS_CUR    3424256           // int [B*1024] scatter cursors    4096

__device__ __forceinline__ int cell_of(float x, float y, float z) {
  int cx = (int)(x*10.f); cx = cx < 0 ? 0 : (cx > 9 ? 9 : cx);
  int cy = (int)(y*10.f); cy = cy < 0 ? 0 : (cy > 9 ? 9 : cy);
  int cz = (int)(z*10.f); cz = cz < 0 ? 0 : (cz > 9 ? 9 : cz);
  return (cx*10 + cy)*10 + cz;
}

// ---------------------------------------------------------------------------
// prep: blocks 0-511 feature transpose (LDS-tiled) + point packing;
//       blocks 512-639 cell counting (global atomics).  grid = 640 x 256.
// ---------------------------------------------------------------------------
__global__ __launch_bounds__(256) void pg_prep(
    const float* __restrict__ sxyz, const float* __restrict__ smask,
    const float* __restrict__ sfeat, float4* __restrict__ pts4,
    float* __restrict__ featT, int* __restrict__ cellCnt)
{
  __shared__ float tile[64*65];
  const int t  = threadIdx.x;
  const int bt = blockIdx.x;

  if (bt >= 512) {        // ---- cell counting: 1 point per thread ----
    const int idx = bt - 512;                // [0,128)
    const int bb  = idx >> 5;
    const int i   = ((idx & 31) << 8) + t;   // [0,8192)
    if (smask[bb*N2D + i] > 0.f) {
      const float* p = sxyz + ((size_t)bb*N2D + i)*3;
      atomicAdd(&cellCnt[bb*1024 + cell_of(p[0], p[1], p[2])], 1);
    }
    return;
  }

  // ---- feature transpose tile + raw point packing ----
  const int b  = bt >> 7;
  const int j0 = (bt & 127) * 64;
  if (t < 64) {
    const int g = bt*64 + t;          // 512*64 = B*N2
    pts4[g] = make_float4(sxyz[g*3+0], sxyz[g*3+1], sxyz[g*3+2], 0.f);
  }
  const float* src = sfeat + (size_t)(b*CIN)*N2D + j0;
#pragma unroll
  for (int i = 0; i < 4; ++i) {
    const int c  = i*16 + (t >> 4);
    const int j4 = (t & 15) * 4;
    const float4 v = *(const float4*)(src + (size_t)c*N2D + j4);
    tile[c*65 + j4+0] = v.x;
    tile[c*65 + j4+1] = v.y;
    tile[c*65 + j4+2] = v.z;
    tile[c*65 + j4+3] = v.w;
  }
  __syncthreads();
  float* dstb = featT + (size_t)(b*N2D + j0) * CIN;
#pragma unroll
  for (int r = 0; r < 4; ++r) {
    const int j  = r*16 + (t >> 4);
    const int c4 = (t & 15) * 4;
    float4 v;
    v.x = tile[(c4+0)*65 + j];
    v.y = tile[(c4+1)*65 + j];
    v.z = tile[(c4+2)*65 + j];
    v.w = tile[(c4+3)*65 + j];
    *(float4*)(dstb + j*CIN + c4) = v;
  }
}

// ---------------------------------------------------------------------------
// scan: per-batch exclusive scan of 1000 cell counts -> cellStart + cursors.
// grid = 4 x 256.
// ---------------------------------------------------------------------------
__global__ __launch_bounds__(256) void pg_scan(
    const int* __restrict__ cellCnt, int* __restrict__ cellStart,
    int* __restrict__ cellCur)
{
  __shared__ int off_s[NCELL+1];
  __shared__ int wsum[4];
  const int t    = threadIdx.x;
  const int lane = t & 63;
  const int wv   = t >> 6;
  const int bb   = blockIdx.x;
  const int* cnt = cellCnt + bb*1024;

  int c0 = 0, c1 = 0, c2 = 0, c3 = 0, v = 0;
  if (t < 250) {
    c0 = cnt[t*4+0]; c1 = cnt[t*4+1]; c2 = cnt[t*4+2]; c3 = cnt[t*4+3];
    v = c0 + c1 + c2 + c3;
  }
  int x = v;
#pragma unroll
  for (int off = 1; off < 64; off <<= 1) {
    int y = __shfl_up(x, off);
    if (lane >= off) x += y;
  }
  if (lane == 63) wsum[wv] = x;
  __syncthreads();
  int base = 0;
#pragma unroll
  for (int w = 0; w < 4; ++w) if (w < wv) base += wsum[w];
  const int excl = base + x - v;
  if (t < 250) {
    int o = excl;
    off_s[t*4+0] = o; o += c0;
    off_s[t*4+1] = o; o += c1;
    off_s[t*4+2] = o; o += c2;
    off_s[t*4+3] = o;
  }
  if (t == 0) off_s[NCELL] = wsum[0]+wsum[1]+wsum[2]+wsum[3];
  __syncthreads();
  for (int i = t; i < NCELL; i += 256) {
    const int o = off_s[i];
    cellStart[bb*(NCELL+1) + i] = o;
    cellCur[bb*1024 + i] = o;
  }
  if (t == 0) cellStart[bb*(NCELL+1) + NCELL] = off_s[NCELL];
}

// ---------------------------------------------------------------------------
// scatter: place points into bins via global cursors.  grid = 128 x 256.
// ---------------------------------------------------------------------------
__global__ __launch_bounds__(256) void pg_scatter(
    const float* __restrict__ sxyz, const float* __restrict__ smask,
    int* __restrict__ cellCur, float4* __restrict__ bpts)
{
  const int idx = blockIdx.x;
  const int bb  = idx >> 5;
  const int i   = ((idx & 31) << 8) + threadIdx.x;
  if (smask[bb*N2D + i] > 0.f) {
    const float* p = sxyz + ((size_t)bb*N2D + i)*3;
    const float px = p[0], py = p[1], pz = p[2];
    const int pos = atomicAdd(&cellCur[bb*1024 + cell_of(px,py,pz)], 1);
    bpts[(size_t)bb*N2D + pos] = make_float4(px, py, pz, __int_as_float(i));
  }
}

// ---------------------------------------------------------------------------
// main: binned ordered ball query + kernel-point weights + weighted feature
// sum + fused 1x1 conv.  grid = 2048 x 256 (1 query/wave).
// Phases 1/2a/2b are WAVE-LOCAL (no __syncthreads); single barrier before
// the fused-conv epilogue.  LDS ~12.4 KB.
// ---------------------------------------------------------------------------
__global__ __launch_bounds__(256) void pg_main(
    const float* __restrict__ qxyz, const float* __restrict__ qmask,
    const float4* __restrict__ pts4, const float4* __restrict__ bpts,
    const int* __restrict__ cellStart, const float* __restrict__ featT,
    const float* __restrict__ Kp, const float* __restrict__ KW,
    const float* __restrict__ Wout, float* __restrict__ out2)
{
  __shared__ __align__(16) int  s_cand[QPB][MAXC];   // candidate j lists
  __shared__ int2               s_im[QPB][NSAMP];    // (j, k-mask) per slot
  __shared__ float              s_w[QPB*NSAMP*17];   // influence weights (pad 17)
  __shared__ float              s_xq[QPB*68];        // conv x rows (pad 68, 16B-mult)

  const int t    = threadIdx.x;
  const int lane = t & 63;
  const int wv   = t >> 6;
  const int gbase = blockIdx.x * QPB;        // 2048 % 4 == 0 -> single batch
  const int b     = gbase >> 11;
  const uint64_t lt = (1ull << lane) - 1ull;

  const int g = gbase + wv;                  // this wave's query
  const float qx = qxyz[g*3+0], qy = qxyz[g*3+1], qz = qxyz[g*3+2];

  // ---- phase 1: candidate walk with SGPR segment tables ----
  const float4* bptsb = bpts + (size_t)b*N2D;
  int cq;                                    // min(C, 32), uniform in registers
  {
    int cx0 = (int)((qx-CMARG)*10.f); if (cx0 < 0) cx0 = 0;
    int cx1 = (int)((qx+CMARG)*10.f); if (cx1 > 9) cx1 = 9;
    int cy0 = (int)((qy-CMARG)*10.f); if (cy0 < 0) cy0 = 0;
    int cy1 = (int)((qy+CMARG)*10.f); if (cy1 > 9) cy1 = 9;
    int cz0 = (int)((qz-CMARG)*10.f); if (cz0 < 0) cz0 = 0;
    int cz1 = (int)((qz+CMARG)*10.f); if (cz1 > 9) cz1 = 9;
    const int ny = cy1 - cy0 + 1;
    const int npair = (cx1 - cx0 + 1) * ny;  // <= 9

    int len = 0, rs = 0;
    if (lane < npair) {
      const int cx = cx0 + lane / ny;
      const int cy = cy0 + lane % ny;
      const int* csb = cellStart + b*(NCELL+1) + (cx*10 + cy)*10;
      rs  = csb[cz0];
      len = csb[cz1 + 1] - rs;
    }
    int pc = len;                            // inclusive prefix over low 16 lanes
#pragma unroll
    for (int off = 1; off < 16; off <<= 1) {
      int y = __shfl_up(pc, off);
      if (lane >= off) pc += y;
    }
    const int tot   = __shfl(pc, 15);
    const int excl  = pc - len;
    const int sbase = rs - excl;

    // broadcast segment tables to SGPRs (literal lane -> scalar regs)
    int segc[9], segb[9];
#pragma unroll
    for (int e = 0; e < 9; ++e) {
      const int ce = __builtin_amdgcn_readlane(excl,  e);
      const int be = __builtin_amdgcn_readlane(sbase, e);
      segc[e] = (e < npair) ? ce : INT_MAX;
      segb[e] = (e < npair) ? be : 0;
    }

    int ccnt = 0;
    for (int base0 = 0; base0 < tot; base0 += 64) {
      const int idx = base0 + lane;
      bool ok = false; int jj = 0;
      if (idx < tot) {
        int bb2 = segb[0];                   // branchless segment select
#pragma unroll
        for (int e = 1; e < 9; ++e) if (segc[e] <= idx) bb2 = segb[e];
        const float4 pt = bptsb[bb2 + idx];
        const float dx = pt.x - qx, dy = pt.y - qy, dz = pt.z - qz;
        ok = (dx*dx + dy*dy + dz*dz) < RAD2;
        jj = __float_as_int(pt.w);
      }
      const uint64_t m = __ballot(ok);
      if (ok) {
        const int pos = ccnt + __popcll(m & lt);
        if (pos < MAXC) s_cand[wv][pos] = jj;
      }
      ccnt += (int)__popcll(m);
    }
    const int C = ccnt < MAXC ? ccnt : MAXC;
    const int C4 = (C + 3) & ~3;
    if (C + lane < C4) s_cand[wv][C + lane] = INT_MAX;  // pad to x4

    // rank-select 32 smallest j via int4 LDS reads (within-wave RAW on LDS)
    int jA = (lane      < C) ? s_cand[wv][lane]      : INT_MAX;
    int jB = (lane + 64 < C) ? s_cand[wv][lane + 64] : INT_MAX;
    int rA = 0, rB = 0;
    for (int e = 0; e < C4; e += 4) {
      const int4 v4 = *(const int4*)&s_cand[wv][e];
      rA += (v4.x < jA) + (v4.y < jA) + (v4.z < jA) + (v4.w < jA);
      rB += (v4.x < jB) + (v4.y < jB) + (v4.z < jB) + (v4.w < jB);
    }
    if (lane      < C && rA < NSAMP) s_im[wv][rA].x = jA;
    if (lane + 64 < C && rB < NSAMP) s_im[wv][rB].x = jB;
    cq = C < NSAMP ? C : NSAMP;
  }

  // ---- phase 2a (wave-local): pad-normalize, rel vector, k-weights ----
  {
    const int s    = lane & 31;
    const int half = lane >> 5;
    const int raw  = s_im[wv][s].x;
    const int r0   = s_im[wv][0].x;
    const int j = (s < cq) ? raw : (cq > 0 ? r0 : 0);
    if (half == 0) s_im[wv][s].x = j;       // normalized idx for phase 2b

    const float4 pj = pts4[b*N2D + j];
    const float rx = pj.x - qx;
    const float ry = pj.y - qy;
    const float rz = pj.z - qz;

    unsigned msk = 0u;
#pragma unroll
    for (int ki = 0; ki < 8; ++ki) {
      const int k = half*8 + ki;            // halves cover k 0-7 / 8-14 in parallel
      if (k < NKP) {
        const float dx = rx - Kp[k*3+0];
        const float dy = ry - Kp[k*3+1];
        const float dz = rz - Kp[k*3+2];
        const float dd = dx*dx + dy*dy + dz*dz;
        const float w = 1.0f - sqrtf(dd) * INV_EXT;
        if (w > 0.0f) {
          s_w[(wv*NSAMP + s)*17 + k] = w;
          msk |= (1u << k);
        }
      }
    }
    msk |= (unsigned)__shfl_xor((int)msk, 32);   // combine halves
    if (half == 0) s_im[wv][s].y = (int)msk;
  }

  // ---- phase 2b (wave-local): weighted feature aggregation (lane=channel) --
  {
    float kw[NKP];
#pragma unroll
    for (int k = 0; k < NKP; ++k) kw[k] = KW[k*CIN + lane];

    const float fpad = 1.0f - qmask[g];
    const int cqs = __builtin_amdgcn_readfirstlane(cq);

    float ft[NSAMP];
#pragma unroll
    for (int s = 0; s < NSAMP; ++s) {
      const int j = __builtin_amdgcn_readfirstlane(s_im[wv][s].x);
      ft[s] = featT[(size_t)(b*N2D + j)*CIN + lane];
    }

    float acc = 0.0f;
#pragma unroll
    for (int s = 0; s < NSAMP; ++s) {
      const float fm = ((s < cqs) ? 1.0f : 0.0f) + fpad;
      if (fm != 0.0f) {
        const unsigned mk =
            (unsigned)__builtin_amdgcn_readfirstlane(s_im[wv][s].y);
        if (mk != 0u) {
          const float* wp = &s_w[(wv*NSAMP + s)*17];
          float wsum = 0.0f;
#pragma unroll
          for (int k = 0; k < NKP; ++k)
            if (mk & (1u << k)) wsum += wp[k] * kw[k];
          acc = fmaf(fm*wsum, ft[s], acc);
        }
      }
    }
    s_xq[wv*68 + lane] = acc;
  }
  __syncthreads();                           // the ONLY block barrier

  // ---- epilogue: fused 1x1 conv, 256 threads x 2 outputs, b128 reads ----
  {
    const int n4 = t & 3;
    const int og = t >> 2;
    const int gq = gbase + n4;
    const int nn = gq & 2047;
    const float4* xr = (const float4*)&s_xq[n4*68];
    const float4* w0 = (const float4*)(Wout + (og*2+0)*CIN);
    const float4* w1 = (const float4*)(Wout + (og*2+1)*CIN);
    float a0 = 0.f, a1 = 0.f;
#pragma unroll
    for (int c4 = 0; c4 < 16; ++c4) {
      const float4 x4 = xr[c4];
      const float4 wa = w0[c4];
      const float4 wb = w1[c4];
      a0 = fmaf(wa.x, x4.x, fmaf(wa.y, x4.y, fmaf(wa.z, x4.z, fmaf(wa.w, x4.w, a0))));
      a1 = fmaf(wb.x, x4.x, fmaf(wb.y, x4.y, fmaf(wb.z, x4.z, fmaf(wb.w, x4.w, a1))));
    }
    float* ob = out2 + (size_t)(b*COUT + og*2)*N1D + nn;
    ob[0]   = a0;
    ob[N1D] = a1;
  }
}

// ---------------------------------------------------------------------------
// finish: per-(b,o) block; redundantly computes channel-o batch stats from
// L2-hot out2, then normalizes its own row from registers.  grid = 512 x 256.
// ---------------------------------------------------------------------------
__global__ __launch_bounds__(256) void pg_finish(
    const float* __restrict__ out2, const float* __restrict__ gamma,
    const float* __restrict__ beta, float* __restrict__ dout)
{
  __shared__ float red[8];
  __shared__ float mv[2];
  const int t  = threadIdx.x;
  const int o  = blockIdx.x & 127;
  const int bb = blockIdx.x >> 7;
  float4 f[4][2];
  float s1 = 0.f, s2 = 0.f;
#pragma unroll
  for (int r = 0; r < BATCH; ++r) {
    const float4* p = (const float4*)(out2 + (size_t)(r*COUT + o)*N1D);
#pragma unroll
    for (int i = 0; i < 2; ++i) {
      const float4 x = p[i*256 + t];
      f[r][i] = x;
      s1 += x.x + x.y + x.z + x.w;
      s2 += x.x*x.x + x.y*x.y + x.z*x.z + x.w*x.w;
    }
  }
#pragma unroll
  for (int off = 32; off; off >>= 1) {
    s1 += __shfl_xor(s1, off);
    s2 += __shfl_xor(s2, off);
  }
  const int wv = t >> 6;
  if ((t & 63) == 0) { red[wv] = s1; red[4+wv] = s2; }
  __syncthreads();
  if (t == 0) {
    const float inv = 1.0f / (float)(BATCH*N1D);
    const float mean = (red[0]+red[1]+red[2]+red[3]) * inv;
    const float var  = (red[4]+red[5]+red[6]+red[7]) * inv - mean*mean;
    mv[0] = mean;
    mv[1] = rsqrtf(var + BN_EPS);
  }
  __syncthreads();
  const float mean = mv[0];
  const float ga = gamma[o] * mv[1];
  const float be = beta[o];
  float4* dp = (float4*)(dout + (size_t)(bb*COUT + o)*N1D);
#pragma unroll
  for (int i = 0; i < 2; ++i) {
    const float4 x = f[bb][i];
    float4 y;
    y.x = fmaxf((x.x - mean)*ga + be, 0.0f);
    y.y = fmaxf((x.y - mean)*ga + be, 0.0f);
    y.z = fmaxf((x.z - mean)*ga + be, 0.0f);
    y.w = fmaxf((x.w - mean)*ga + be, 0.0f);
    dp[i*256 + t] = y;
  }
}

extern "C" void kernel_launch(void* const* d_in, const int* in_sizes, int n_in,
                              void* d_out, int out_size, void* d_ws, size_t ws_size,
                              hipStream_t stream)
{
  const float* qxyz  = (const float*)d_in[0];
  const float* sxyz  = (const float*)d_in[1];
  const float* qmask = (const float*)d_in[2];
  const float* smask = (const float*)d_in[3];
  const float* sfeat = (const float*)d_in[4];
  const float* Kp    = (const float*)d_in[5];
  const float* KW    = (const float*)d_in[6];
  const float* Wout  = (const float*)d_in[7];
  const float* gamma = (const float*)d_in[8];
  const float* beta  = (const float*)d_in[9];
  float* ws = (float*)d_ws;
  float4* pts4 = (float4*)(ws + WS_PTS4);
  float4* bpts = (float4*)(ws + WS_BPTS);
  float* featT = ws + WS_FEATT;
  float* out2  = ws + WS_OUT2;
  int*   cellS = (int*)(ws + WS_CS);
  int*   cellC = (int*)(ws + WS_CNT);
  int*   cellU = (int*)(ws + WS_CUR);
  float* dst   = (float*)d_out;

  hipMemsetAsync(cellC, 0, BATCH*1024*sizeof(int), stream);
  pg_prep   <<<640,  256, 0, stream>>>(sxyz, smask, sfeat, pts4, featT, cellC);
  pg_scan   <<<4,    256, 0, stream>>>(cellC, cellS, cellU);
  pg_scatter<<<128,  256, 0, stream>>>(sxyz, smask, cellU, bpts);
  pg_main   <<<2048, 256, 0, stream>>>(qxyz, qmask, pts4, bpts, cellS, featT,
                                       Kp, KW, Wout, out2);
  pg_finish <<<512,  256, 0, stream>>>(out2, gamma, beta, dst);
}